// Round 9
// baseline (131.775 us; speedup 1.0000x reference)
//
#include <hip/hip_runtime.h>
#include <hip/hip_bf16.h>

#define B_ 32
#define N_ 128
#define D_ 512
#define A_ 512
#define R_ (B_*N_)     // 4096 rows
#define OC 1024        // fused Y cols (E1 | E2)
#define CEXP 2.8853900817779268f   // 2*log2(e)

typedef __attribute__((ext_vector_type(8)))  short frag_ab;   // 8 bf16
typedef __attribute__((ext_vector_type(16))) float frag_c;    // 16 f32 (32x32 acc)

__device__ inline unsigned pack2bf(float a, float b) {
    unsigned ua = __builtin_bit_cast(unsigned, a) + 0x8000u;
    unsigned ub = __builtin_bit_cast(unsigned, b) + 0x8000u;
    return __builtin_amdgcn_perm(ub, ua, 0x07060302);
}
__device__ inline float bf2f_lo(unsigned u){ return __builtin_bit_cast(float, u << 16); }
__device__ inline float bf2f_hi(unsigned u){ return __builtin_bit_cast(float, u & 0xffff0000u); }

// ---------------- Kernel 0: fp32 -> bf16 conversion of X, W1, W2 ----------
__global__ __launch_bounds__(256) void k0_cvt(
    const float* __restrict__ X, const float* __restrict__ W1,
    const float* __restrict__ W2,
    unsigned short* __restrict__ Xb, unsigned short* __restrict__ W1b,
    unsigned short* __restrict__ W2b)
{
    const int NX = R_*D_/8, NW = A_*D_/8;
    int i = blockIdx.x*256 + threadIdx.x;
    const float* src; unsigned short* dst; int off;
    if (i < NX)            { src = X;  dst = Xb;  off = i; }
    else if (i < NX+NW)    { src = W1; dst = W1b; off = i-NX; }
    else if (i < NX+2*NW)  { src = W2; dst = W2b; off = i-NX-NW; }
    else return;
    float4 a = ((const float4*)src)[off*2];
    float4 c = ((const float4*)src)[off*2+1];
    uint4 o;
    o.x = pack2bf(a.x,a.y); o.y = pack2bf(a.z,a.w);
    o.z = pack2bf(c.x,c.y); o.w = pack2bf(c.z,c.w);
    ((uint4*)dst)[off] = o;
}

// ---------------- Kernel 1: Yb = bf16(exp2(C*(X*[W1;W2]^T + [b1;b2]))) ----
// 128x128 tile, BK=32, 4 waves (2x2), 2x2 of 32x32x16 MFMA per wave.
#define LDK1 36

__global__ __launch_bounds__(256) void k1_mfma(
    const unsigned short* __restrict__ Xb,
    const unsigned short* __restrict__ W1b, const float* __restrict__ b1,
    const unsigned short* __restrict__ W2b, const float* __restrict__ b2,
    unsigned short* __restrict__ Yb)
{
    __shared__ unsigned short As[2][128*LDK1];
    __shared__ unsigned short Bs[2][128*LDK1];

    const int t = threadIdx.x, lane = t&63, wid = t>>6;
    const int wr = wid>>1, wc = wid&1;          // wave 64x64 quadrant
    const int row0 = blockIdx.x*128, col0 = blockIdx.y*128;
    const unsigned short* Wb = (col0 < A_) ? W1b : W2b;
    const float* bb = (col0 < A_) ? b1 : b2;
    const int wrow0 = col0 & (A_-1);

    const int srow = t>>1;          // 0..127 (staging row)
    const int scol = (t&1)*16;      // 0 or 16 (elems)

    frag_c acc[2][2];
#pragma unroll
    for (int i=0;i<2;++i)
#pragma unroll
        for (int j=0;j<2;++j)
#pragma unroll
            for (int r=0;r<16;++r) acc[i][j][r] = 0.f;

    const int fr = lane & 31;          // M/N row within 32-tile
    const int ko = (lane >> 5) * 8;    // k-offset 0 or 8

    { // prologue: stage K-chunk 0 into buf0
        const unsigned short* px = &Xb[(size_t)(row0 +srow)*D_ + scol];
        const unsigned short* pw = &Wb[(size_t)(wrow0+srow)*D_ + scol];
        uint4 a0 = *(const uint4*)px, a1 = *(const uint4*)(px+8);
        uint4 b0 = *(const uint4*)pw, b1v = *(const uint4*)(pw+8);
        *(uint4*)&As[0][srow*LDK1 + scol]     = a0;
        *(uint4*)&As[0][srow*LDK1 + scol + 8] = a1;
        *(uint4*)&Bs[0][srow*LDK1 + scol]     = b0;
        *(uint4*)&Bs[0][srow*LDK1 + scol + 8] = b1v;
    }
    __syncthreads();

#pragma unroll
    for (int s = 0; s < 16; ++s) {
        const int cur = s & 1;
        uint4 a0, a1, b0, b1v;
        if (s < 15) {   // early-issue next K-chunk's loads
            const int k0 = (s+1)*32;
            const unsigned short* px = &Xb[(size_t)(row0 +srow)*D_ + k0 + scol];
            const unsigned short* pw = &Wb[(size_t)(wrow0+srow)*D_ + k0 + scol];
            a0 = *(const uint4*)px; a1 = *(const uint4*)(px+8);
            b0 = *(const uint4*)pw; b1v = *(const uint4*)(pw+8);
        }
        frag_ab af[2][2], bf[2][2];
#pragma unroll
        for (int mt=0; mt<2; ++mt)
#pragma unroll
            for (int ks=0; ks<2; ++ks) {
                af[mt][ks] = *(const frag_ab*)&As[cur][(wr*64+mt*32+fr)*LDK1 + ks*16 + ko];
                bf[mt][ks] = *(const frag_ab*)&Bs[cur][(wc*64+mt*32+fr)*LDK1 + ks*16 + ko];
            }
#pragma unroll
        for (int ks=0; ks<2; ++ks)
#pragma unroll
            for (int mt=0; mt<2; ++mt)
#pragma unroll
                for (int nt=0; nt<2; ++nt)
                    acc[mt][nt] = __builtin_amdgcn_mfma_f32_32x32x16_bf16(
                        af[mt][ks], bf[nt][ks], acc[mt][nt], 0, 0, 0);
        if (s < 15) {   // write-late into the other buffer
            *(uint4*)&As[cur^1][srow*LDK1 + scol]     = a0;
            *(uint4*)&As[cur^1][srow*LDK1 + scol + 8] = a1;
            *(uint4*)&Bs[cur^1][srow*LDK1 + scol]     = b0;
            *(uint4*)&Bs[cur^1][srow*LDK1 + scol + 8] = b1v;
        }
        __syncthreads();
    }

    // epilogue: 32x32 C/D layout col=lane&31, row=(reg&3)+8*(reg>>2)+4*(lane>>5)
#pragma unroll
    for (int mt=0; mt<2; ++mt) {
        const int rbase = row0 + wr*64 + mt*32 + 4*(lane>>5);
#pragma unroll
        for (int nt=0; nt<2; ++nt) {
            const int cc = col0 + wc*64 + nt*32 + (lane&31);
            const float bias = bb[cc & (A_-1)];
#pragma unroll
            for (int r=0; r<16; ++r) {
                const int rr = rbase + (r&3) + 8*(r>>2);
                float e = __builtin_amdgcn_exp2f(CEXP*(acc[mt][nt][r] + bias));
                Yb[(size_t)rr*OC + cc] =
                    (unsigned short)((__builtin_bit_cast(unsigned, e) + 0x8000u) >> 16);
            }
        }
    }
}

// ---------------- Kernel 2 ----------------
// out[b,i,j] += wsum_q - 2*sum_{a in quarter} wo[a]/(1+E1[j,a]*E2[i+1,a])
// Block: 64j x 64i x 128a (a-split x4). 4x4 per thread -> 2.25 B LDS/tanh.
// One staged chunk, one barrier. XOR swizzle c^=((r>>2)&7)<<2 -> conflict-free
// strided-row float4 reads. Reciprocal pairing halves rcp count.
#define LDW 132

__device__ inline int swz(int r, int c) { return r*LDW + (c ^ (((r>>2)&7)<<2)); }

__global__ __launch_bounds__(256) void k2_tanh(
    const unsigned short* __restrict__ Yb,
    const float* __restrict__ Wout, const float* __restrict__ bout,
    float* __restrict__ out)
{
    __shared__ float e1s[64*LDW];
    __shared__ float e2s[64*LDW];
    __shared__ float wo[128];
    __shared__ float wsum_s[4];

    const int t  = threadIdx.x;
    const int jt = blockIdx.x & 1;        // j half: 0..1
    const int it = blockIdx.x >> 1;       // i half: 0..1
    const int ah = blockIdx.y;            // a quarter: 0..3
    const int b  = blockIdx.z;
    const int abase = ah << 7;

    {   // wo slice + partial wsum
        float w = (t < 128) ? Wout[abase + t] : 0.f;
        if (t < 128) wo[t] = w;
#pragma unroll
        for (int off=32; off>=1; off>>=1) w += __shfl_down(w, off, 64);
        if ((t&63)==0) wsum_s[t>>6] = w;
    }

    const unsigned short* yb = Yb + (size_t)b*N_*OC;
    const int sr = t>>4;           // 0..15 (staging row, q adds 16)
    const int sc = (t&15)*8;       // 0..120 elems

#pragma unroll
    for (int q=0; q<4; ++q) {
        const int r = q*16 + sr;                  // 0..63
        uint4 v1 = *(const uint4*)&yb[(size_t)(jt*64 + r)*OC + abase + sc];
        int i2 = it*64 + r + 1; if (i2 > 127) i2 = 127;
        uint4 v2 = *(const uint4*)&yb[(size_t)i2*OC + A_ + abase + sc];
        *(float4*)&e1s[swz(r, sc)]   = float4{bf2f_lo(v1.x),bf2f_hi(v1.x),bf2f_lo(v1.y),bf2f_hi(v1.y)};
        *(float4*)&e1s[swz(r, sc+4)] = float4{bf2f_lo(v1.z),bf2f_hi(v1.z),bf2f_lo(v1.w),bf2f_hi(v1.w)};
        *(float4*)&e2s[swz(r, sc)]   = float4{bf2f_lo(v2.x),bf2f_hi(v2.x),bf2f_lo(v2.y),bf2f_hi(v2.y)};
        *(float4*)&e2s[swz(r, sc+4)] = float4{bf2f_lo(v2.z),bf2f_hi(v2.z),bf2f_lo(v2.w),bf2f_hi(v2.w)};
    }
    __syncthreads();

    const int jl = t&15, il = t>>4;
    float acc[4][4];
#pragma unroll
    for (int kj=0;kj<4;++kj)
#pragma unroll
        for (int ki=0;ki<4;++ki) acc[kj][ki] = 0.f;

#pragma unroll 1
    for (int c=0; c<128; c+=4) {
        float4 u[4], v[4];
#pragma unroll
        for (int kj=0;kj<4;++kj) u[kj] = *(const float4*)&e1s[swz(4*jl+kj, c)];
#pragma unroll
        for (int ki=0;ki<4;++ki) v[ki] = *(const float4*)&e2s[swz(4*il+ki, c)];
        float4 w4 = *(const float4*)&wo[c];
#pragma unroll
        for (int kj=0;kj<4;++kj)
#pragma unroll
            for (int ki=0;ki<4;++ki) {
                float r0 = fmaf(u[kj].x, v[ki].x, 1.f);
                float s0 = fmaf(u[kj].y, v[ki].y, 1.f);
                acc[kj][ki] = fmaf(fmaf(w4.x, s0, w4.y*r0),
                                   __builtin_amdgcn_rcpf(r0*s0), acc[kj][ki]);
                float r1 = fmaf(u[kj].z, v[ki].z, 1.f);
                float s1 = fmaf(u[kj].w, v[ki].w, 1.f);
                acc[kj][ki] = fmaf(fmaf(w4.z, s1, w4.w*r1),
                                   __builtin_amdgcn_rcpf(r1*s1), acc[kj][ki]);
            }
    }

    const float wsum = wsum_s[0]+wsum_s[1]+wsum_s[2]+wsum_s[3];
    const float base = wsum + (ah ? 0.f : bout[0]);
    float* ob = out + (size_t)b*127*128;
#pragma unroll
    for (int ki=0;ki<4;++ki) {
        const int i0 = it*64 + 4*il + ki;
        if (i0 < 127) {
#pragma unroll
            for (int kj=0;kj<4;++kj) {
                const int j0 = jt*64 + 4*jl + kj;
                atomicAdd(&ob[i0*128 + j0], base - 2.f*acc[kj][ki]);
            }
        }
    }
}

extern "C" void kernel_launch(void* const* d_in, const int* in_sizes, int n_in,
                              void* d_out, int out_size, void* d_ws, size_t ws_size,
                              hipStream_t stream) {
    const float* x    = (const float*)d_in[0];
    const float* W1   = (const float*)d_in[1];
    const float* b1   = (const float*)d_in[2];
    const float* W2   = (const float*)d_in[3];
    const float* b2   = (const float*)d_in[4];
    const float* Wout = (const float*)d_in[5];
    const float* bout = (const float*)d_in[6];
    float* out = (float*)d_out;

    char* ws = (char*)d_ws;
    unsigned short* Yb  = (unsigned short*)ws;                              // 8 MB
    unsigned short* Xb  = (unsigned short*)(ws + (8u<<20));                 // 4 MB
    unsigned short* W1b = (unsigned short*)(ws + (12u<<20));                // 512 KB
    unsigned short* W2b = (unsigned short*)(ws + (12u<<20) + (1u<<19));     // 512 KB

    k0_cvt<<<1280, 256, 0, stream>>>(x, W1, W2, Xb, W1b, W2b);

    dim3 g1(R_/128, OC/128);     // (32, 8) = 256 blocks
    k1_mfma<<<g1, 256, 0, stream>>>(Xb, W1b, b1, W2b, b2, Yb);

    hipMemsetAsync(d_out, 0, (size_t)out_size*sizeof(float), stream);

    dim3 g2(4, 4, B_);           // (jt|it, ah, b) = 512 blocks, 2/CU
    k2_tanh<<<g2, 256, 0, stream>>>(Yb, Wout, bout, out);
}

// Round 10
// 122.940 us; speedup vs baseline: 1.0719x; 1.0719x over previous
//
#include <hip/hip_runtime.h>
#include <hip/hip_bf16.h>

#define B_ 32
#define N_ 128
#define D_ 512
#define A_ 512
#define R_ (B_*N_)     // 4096 rows
#define OC 1024        // fused Y cols (E1 | E2)
#define CEXP 2.8853900817779268f   // 2*log2(e)

typedef __attribute__((ext_vector_type(8)))  short frag_ab;   // 8 bf16
typedef __attribute__((ext_vector_type(16))) float frag_c;    // 16 f32 (32x32 acc)

__device__ inline unsigned pack2bf(float a, float b) {
    unsigned ua = __builtin_bit_cast(unsigned, a) + 0x8000u;
    unsigned ub = __builtin_bit_cast(unsigned, b) + 0x8000u;
    return __builtin_amdgcn_perm(ub, ua, 0x07060302);
}
__device__ inline float bf2f_lo(unsigned u){ return __builtin_bit_cast(float, u << 16); }
__device__ inline float bf2f_hi(unsigned u){ return __builtin_bit_cast(float, u & 0xffff0000u); }

// ---------------- Kernel 0: fp32 -> bf16 conversion of X, W1, W2 ----------
__global__ __launch_bounds__(256) void k0_cvt(
    const float* __restrict__ X, const float* __restrict__ W1,
    const float* __restrict__ W2,
    unsigned short* __restrict__ Xb, unsigned short* __restrict__ W1b,
    unsigned short* __restrict__ W2b)
{
    const int NX = R_*D_/8, NW = A_*D_/8;
    int i = blockIdx.x*256 + threadIdx.x;
    const float* src; unsigned short* dst; int off;
    if (i < NX)            { src = X;  dst = Xb;  off = i; }
    else if (i < NX+NW)    { src = W1; dst = W1b; off = i-NX; }
    else if (i < NX+2*NW)  { src = W2; dst = W2b; off = i-NX-NW; }
    else return;
    float4 a = ((const float4*)src)[off*2];
    float4 c = ((const float4*)src)[off*2+1];
    uint4 o;
    o.x = pack2bf(a.x,a.y); o.y = pack2bf(a.z,a.w);
    o.z = pack2bf(c.x,c.y); o.w = pack2bf(c.z,c.w);
    ((uint4*)dst)[off] = o;
}

// ---------------- Kernel 1: Yb = bf16(exp2(C*(X*[W1;W2]^T + [b1;b2]))) ----
// 64x64 tile, BK=64, 4 waves each one 32x32 acc. Grid 1024 = 4 blk/CU.
// LDS: [64 rows][8 slots of 16B], phys_slot = slot ^ (row&7) (both sides).
// Rows 128B apart (bank-neutral), all accesses 16B-aligned, reads at floor.
__global__ __launch_bounds__(256) void k1_mfma(
    const unsigned short* __restrict__ Xb,
    const unsigned short* __restrict__ W1b, const float* __restrict__ b1,
    const unsigned short* __restrict__ W2b, const float* __restrict__ b2,
    unsigned short* __restrict__ Yb)
{
    __shared__ unsigned short As[2][64*64];
    __shared__ unsigned short Bs[2][64*64];

    const int t = threadIdx.x, lane = t&63, wid = t>>6;
    const int wr = wid>>1, wc = wid&1;
    const int row0 = blockIdx.x*64, col0 = blockIdx.y*64;
    const unsigned short* Wb = (col0 < A_) ? W1b : W2b;
    const float* bb = (col0 < A_) ? b1 : b2;
    const int wrow0 = col0 & (A_-1);

    const int sr = t>>2;          // staging row 0..63
    const int ss = (t&3)*2;       // staging slots: ss, ss+1
    const int sf = sr & 7;        // write-side XOR key

    frag_c acc;
#pragma unroll
    for (int r=0;r<16;++r) acc[r] = 0.f;

    const int fr = lane & 31;
    const int hs = lane >> 5;              // k-half
    const int arow = wr*32 + fr, af_f = arow & 7;
    const int brow = wc*32 + fr, bf_f = brow & 7;

    { // prologue: stage K-chunk 0 into buf0
        const unsigned short* px = &Xb[(size_t)(row0 +sr)*D_ + ss*8];
        const unsigned short* pw = &Wb[(size_t)(wrow0+sr)*D_ + ss*8];
        uint4 a0 = *(const uint4*)px, a1 = *(const uint4*)(px+8);
        uint4 b0 = *(const uint4*)pw, b1v = *(const uint4*)(pw+8);
        *(uint4*)&As[0][sr*64 + (( ss   ^sf)<<3)] = a0;
        *(uint4*)&As[0][sr*64 + (((ss+1)^sf)<<3)] = a1;
        *(uint4*)&Bs[0][sr*64 + (( ss   ^sf)<<3)] = b0;
        *(uint4*)&Bs[0][sr*64 + (((ss+1)^sf)<<3)] = b1v;
    }
    __syncthreads();

#pragma unroll
    for (int s = 0; s < 8; ++s) {
        const int cur = s & 1;
        uint4 a0, a1, b0, b1v;
        if (s < 7) {   // early-issue next K-chunk's loads
            const int k0 = (s+1)*64;
            const unsigned short* px = &Xb[(size_t)(row0 +sr)*D_ + k0 + ss*8];
            const unsigned short* pw = &Wb[(size_t)(wrow0+sr)*D_ + k0 + ss*8];
            a0 = *(const uint4*)px; a1 = *(const uint4*)(px+8);
            b0 = *(const uint4*)pw; b1v = *(const uint4*)(pw+8);
        }
        frag_ab af[4], bf[4];
#pragma unroll
        for (int ks=0; ks<4; ++ks) {
            const int slot = ks*2 + hs;
            af[ks] = *(const frag_ab*)&As[cur][arow*64 + ((slot^af_f)<<3)];
            bf[ks] = *(const frag_ab*)&Bs[cur][brow*64 + ((slot^bf_f)<<3)];
        }
#pragma unroll
        for (int ks=0; ks<4; ++ks)
            acc = __builtin_amdgcn_mfma_f32_32x32x16_bf16(af[ks], bf[ks], acc, 0, 0, 0);
        if (s < 7) {   // write-late into the other buffer
            *(uint4*)&As[cur^1][sr*64 + (( ss   ^sf)<<3)] = a0;
            *(uint4*)&As[cur^1][sr*64 + (((ss+1)^sf)<<3)] = a1;
            *(uint4*)&Bs[cur^1][sr*64 + (( ss   ^sf)<<3)] = b0;
            *(uint4*)&Bs[cur^1][sr*64 + (((ss+1)^sf)<<3)] = b1v;
        }
        __syncthreads();
    }

    // epilogue: 32x32 C/D layout col=lane&31, row=(reg&3)+8*(reg>>2)+4*(lane>>5)
    const int cc = col0 + wc*32 + (lane&31);
    const float bias = bb[cc & (A_-1)];
    const int rbase = row0 + wr*32 + 4*(lane>>5);
#pragma unroll
    for (int r=0; r<16; ++r) {
        const int rr = rbase + (r&3) + 8*(r>>2);
        float e = __builtin_amdgcn_exp2f(CEXP*(acc[r] + bias));
        Yb[(size_t)rr*OC + cc] =
            (unsigned short)((__builtin_bit_cast(unsigned, e) + 0x8000u) >> 16);
    }
}

// ---------------- Kernel 2 ----------------
// P[ac][b][i][j] = wsum_ac - 2*sum_{a in chunk} wo[a]/(1+E1[j,a]*E2[i+1,a])
// Block: 64j x 64i x 64a. Grid (4,8,32)=1024 = 4 blk/CU, 16 waves/CU.
// bf16 LDS (17 KB), ONE barrier, no chunk loop. 4x4/thread.
// phys_slot = slot ^ ((row>>2)&7): strided-row reads conflict-free.
__global__ __launch_bounds__(256) void k2_tanh(
    const unsigned short* __restrict__ Yb,
    const float* __restrict__ Wout,
    float* __restrict__ P)
{
    __shared__ unsigned short e1s[64*64];
    __shared__ unsigned short e2s[64*64];
    __shared__ float wo[64];
    __shared__ float wsum_s;

    const int t  = threadIdx.x;
    const int jt = blockIdx.x & 1;
    const int it = blockIdx.x >> 1;
    const int ac = blockIdx.y;           // a-chunk 0..7
    const int b  = blockIdx.z;
    const int abase = ac*64;

    if (t < 64) {
        float w = Wout[abase + t];
        wo[t] = w;
#pragma unroll
        for (int off=32; off>=1; off>>=1) w += __shfl_down(w, off, 64);
        if (t == 0) wsum_s = w;
    }

    const unsigned short* yb = Yb + (size_t)b*N_*OC;
    {   // stage E1/E2 chunk (bf16, swizzled)
        const int r  = t>>2;             // 0..63
        const int s0 = (t&3)*2;          // slots s0, s0+1
        const int f  = (r>>2)&7;
        int g2 = it*64 + r + 1; if (g2 > 127) g2 = 127;
        const unsigned short* p1 = &yb[(size_t)(jt*64 + r)*OC + abase + s0*8];
        const unsigned short* p2 = &yb[(size_t)g2*OC + A_ + abase + s0*8];
        uint4 a0 = *(const uint4*)p1, a1 = *(const uint4*)(p1+8);
        uint4 b0 = *(const uint4*)p2, b1v = *(const uint4*)(p2+8);
        *(uint4*)&e1s[r*64 + (( s0   ^f)<<3)] = a0;
        *(uint4*)&e1s[r*64 + (((s0+1)^f)<<3)] = a1;
        *(uint4*)&e2s[r*64 + (( s0   ^f)<<3)] = b0;
        *(uint4*)&e2s[r*64 + (((s0+1)^f)<<3)] = b1v;
    }
    __syncthreads();

    const int jl = t&15, il = t>>4;
    const int fj = jl&7, fi = il&7;
    float acc[4][4];
#pragma unroll
    for (int kj=0;kj<4;++kj)
#pragma unroll
        for (int ki=0;ki<4;++ki) acc[kj][ki] = 0.f;

#pragma unroll
    for (int c8=0; c8<8; ++c8) {
        uint4 V4[4];
#pragma unroll
        for (int ki=0;ki<4;++ki)
            V4[ki] = *(const uint4*)&e2s[(4*il+ki)*64 + ((c8^fi)<<3)];
        float vf[4][8];
#pragma unroll
        for (int ki=0;ki<4;++ki) {
            vf[ki][0]=bf2f_lo(V4[ki].x); vf[ki][1]=bf2f_hi(V4[ki].x);
            vf[ki][2]=bf2f_lo(V4[ki].y); vf[ki][3]=bf2f_hi(V4[ki].y);
            vf[ki][4]=bf2f_lo(V4[ki].z); vf[ki][5]=bf2f_hi(V4[ki].z);
            vf[ki][6]=bf2f_lo(V4[ki].w); vf[ki][7]=bf2f_hi(V4[ki].w);
        }
        float4 wa = *(const float4*)&wo[c8*8];
        float4 wb = *(const float4*)&wo[c8*8 + 4];
#pragma unroll
        for (int kj=0;kj<4;++kj) {
            uint4 U = *(const uint4*)&e1s[(4*jl+kj)*64 + ((c8^fj)<<3)];
            float u0=bf2f_lo(U.x), u1=bf2f_hi(U.x), u2=bf2f_lo(U.y), u3=bf2f_hi(U.y);
            float u4=bf2f_lo(U.z), u5=bf2f_hi(U.z), u6=bf2f_lo(U.w), u7=bf2f_hi(U.w);
#pragma unroll
            for (int ki=0;ki<4;++ki) {
                { float r0=fmaf(u0,vf[ki][0],1.f), s0=fmaf(u1,vf[ki][1],1.f);
                  acc[kj][ki]=fmaf(fmaf(wa.x,s0,wa.y*r0),__builtin_amdgcn_rcpf(r0*s0),acc[kj][ki]); }
                { float r0=fmaf(u2,vf[ki][2],1.f), s0=fmaf(u3,vf[ki][3],1.f);
                  acc[kj][ki]=fmaf(fmaf(wa.z,s0,wa.w*r0),__builtin_amdgcn_rcpf(r0*s0),acc[kj][ki]); }
                { float r0=fmaf(u4,vf[ki][4],1.f), s0=fmaf(u5,vf[ki][5],1.f);
                  acc[kj][ki]=fmaf(fmaf(wb.x,s0,wb.y*r0),__builtin_amdgcn_rcpf(r0*s0),acc[kj][ki]); }
                { float r0=fmaf(u6,vf[ki][6],1.f), s0=fmaf(u7,vf[ki][7],1.f);
                  acc[kj][ki]=fmaf(fmaf(wb.z,s0,wb.w*r0),__builtin_amdgcn_rcpf(r0*s0),acc[kj][ki]); }
            }
        }
    }

    const float base = wsum_s;
    float* Pb = P + ((size_t)(ac*B_ + b))*128*128;
#pragma unroll
    for (int ki=0;ki<4;++ki) {
        const int i0 = it*64 + 4*il + ki;
        float4 o = { base - 2.f*acc[0][ki], base - 2.f*acc[1][ki],
                     base - 2.f*acc[2][ki], base - 2.f*acc[3][ki] };
        *(float4*)&Pb[i0*128 + jt*64 + 4*jl] = o;
    }
}

// ---------------- Kernel 3: out = sum_{ac} P + bout  ----------------
__global__ __launch_bounds__(256) void k3_reduce(
    const float* __restrict__ P, const float* __restrict__ bout,
    float* __restrict__ out)
{
    int o = blockIdx.x*256 + threadIdx.x;
    if (o >= B_*127*128) return;
    const int b = o / (127*128);
    const int rem = o - b*127*128;
    const float* p = P + (size_t)b*16384 + rem;
    float s = bout[0];
#pragma unroll
    for (int q=0; q<8; ++q) s += p[(size_t)q*B_*16384];
    out[o] = s;
}

extern "C" void kernel_launch(void* const* d_in, const int* in_sizes, int n_in,
                              void* d_out, int out_size, void* d_ws, size_t ws_size,
                              hipStream_t stream) {
    const float* x    = (const float*)d_in[0];
    const float* W1   = (const float*)d_in[1];
    const float* b1   = (const float*)d_in[2];
    const float* W2   = (const float*)d_in[3];
    const float* b2   = (const float*)d_in[4];
    const float* Wout = (const float*)d_in[5];
    const float* bout = (const float*)d_in[6];
    float* out = (float*)d_out;

    char* ws = (char*)d_ws;
    unsigned short* Yb  = (unsigned short*)ws;                              // 8 MB
    unsigned short* Xb  = (unsigned short*)(ws + (8u<<20));                 // 4 MB
    unsigned short* W1b = (unsigned short*)(ws + (12u<<20));                // 512 KB
    unsigned short* W2b = (unsigned short*)(ws + (12u<<20) + (1u<<19));     // 512 KB
    float*          P   = (float*)(ws + (16u<<20));                         // 16.8 MB

    k0_cvt<<<1280, 256, 0, stream>>>(x, W1, W2, Xb, W1b, W2b);

    dim3 g1(R_/64, OC/64);       // (64, 16) = 1024 blocks
    k1_mfma<<<g1, 256, 0, stream>>>(Xb, W1b, b1, W2b, b2, Yb);

    dim3 g2(4, 8, B_);           // (jt|it, ac, b) = 1024 blocks
    k2_tanh<<<g2, 256, 0, stream>>>(Yb, Wout, P);

    k3_reduce<<<(B_*127*128 + 255)/256, 256, 0, stream>>>(P, bout, out);
}